// Round 6
// baseline (191.089 us; speedup 1.0000x reference)
//
#include <hip/hip_runtime.h>

// CompanionSSM: 512 blocks (head h x batch-pair bp), 8 waves each, 2 blocks
// co-resident per CU (LDS 58KB).  Cols 0..7 = 2 batches x 4 channels; lanes
// n16>=8 masked for IO (zero columns flow through the math).
// Round-5 overlapped schedule, tightened: 8 groups x 8 chunks, wave 0 =
// dedicated serial scanner, waves 1-7 produce/consume, parity-disjoint R
// buffers with entering-S written IN PLACE over consumed R (r0 trick):
//   iter g: wave0: scan(g)        (R[g&1] -> S in place)
//           w1-7 : consume(g-1)   (S + UB regs -> Y stores)   [same parity]
//                  produce(g+1)   (loads -> UB, R=V@U)        [same parity,
//                                  same wave's own slots, after consume]
// Prep: chains w/o in-loop reductions + deferred dots (r5); V/W/K frag-major
// LDS; T frags in wave-0 regs.  LDS: R 2x16KB (G aliases) + frags 24KB + phi/kv.

#define NKH 256
#define KD  64
#define SL  4096
#define DM  1024

typedef __attribute__((ext_vector_type(8))) short short8;
typedef __attribute__((ext_vector_type(4))) float floatx4;

#define RBUF_OFF  0
#define FV_OFF    32768
#define FW_OFF    40960
#define FK_OFF    49152
#define PHI_OFF   57344
#define KV_OFF    57856
#define LDS_TOTAL 58112

static __device__ __forceinline__ unsigned pack_bf16(float a, float b) {
  union { float f; unsigned u; } ua, ub;
  ua.f = a; ub.f = b;
  return __builtin_amdgcn_perm(ub.u + 0x8000u, ua.u + 0x8000u, 0x07060302u);
}
static __device__ __forceinline__ unsigned short f2bfru(float x) {
  union { float f; unsigned u; } v; v.f = x;
  return (unsigned short)((v.u + 0x8000u) >> 16);
}
static __device__ __forceinline__ float bflo(unsigned d) {
  union { unsigned u; float f; } v; v.u = d << 16; return v.f;
}
static __device__ __forceinline__ float bfhi(unsigned d) {
  union { unsigned u; float f; } v; v.u = d & 0xffff0000u; return v.f;
}
static __device__ __forceinline__ float bf2f(unsigned short s) {
  union { unsigned u; float f; } v; v.u = ((unsigned)s) << 16; return v.f;
}
static __device__ __forceinline__ float wredsum(float x) {
#pragma unroll
  for (int off = 32; off; off >>= 1) x += __shfl_xor(x, off, 64);
  return x;
}
// frag-major 16B-group byte offset for 64x64 bf16: element (row, colg..colg+7)
static __device__ __forceinline__ int fmoff(int row, int colg) {
  return ((((row >> 4) * 2 + (colg >> 5)) * 64 + ((colg >> 3) & 3) * 16 + (row & 15)) << 4);
}

// -------- producer: chunks of group QN -> Rbuf[QN&1], UB kept --------
#define PRODUCE(QN, UBARR) do { \
  char* rbuf_ = lds + RBUF_OFF + ((QN) & 1) * 16384; \
  _Pragma("unroll") \
  for (int ci = 0; ci < 2; ++ci) { \
    const int lq_ = myw + 7 * ci; \
    if (lq_ < 8) { \
      const int qg_ = (QN) * 8 + lq_; \
      float ur_[16]; \
      _Pragma("unroll") \
      for (int j_ = 0; j_ < 16; ++j_) ur_[j_] = 0.f; \
      if (act) { \
        _Pragma("unroll") \
        for (int j_ = 0; j_ < 8; ++j_) { \
          ur_[j_]     = up[(size_t)(qg_*64 +      quad*8 + j_) * DM]; \
          ur_[8 + j_] = up[(size_t)(qg_*64 + 32 + quad*8 + j_) * DM]; \
        } \
      } \
      union { short8 v; unsigned s4[4]; } b2_, b3_; \
      _Pragma("unroll") \
      for (int jj_ = 0; jj_ < 4; ++jj_) { \
        b2_.s4[jj_] = pack_bf16(ur_[2*jj_],     ur_[2*jj_ + 1]); \
        b3_.s4[jj_] = pack_bf16(ur_[8 + 2*jj_], ur_[8 + 2*jj_ + 1]); \
      } \
      UBARR[ci][0] = b2_.v; UBARR[ci][1] = b3_.v; \
      char* slot_ = rbuf_ + lq_ * 2048; \
      _Pragma("unroll") \
      for (int rt_ = 0; rt_ < 4; ++rt_) { \
        const short8 v0_ = *(const short8*)(lds + FV_OFF + (((rt_*2 + 0)*64 + lane) << 4)); \
        const short8 v1_ = *(const short8*)(lds + FV_OFF + (((rt_*2 + 1)*64 + lane) << 4)); \
        floatx4 r_ = {0.f, 0.f, 0.f, 0.f}; \
        r_ = __builtin_amdgcn_mfma_f32_16x16x32_bf16(v0_, UBARR[ci][0], r_, 0,0,0); \
        r_ = __builtin_amdgcn_mfma_f32_16x16x32_bf16(v1_, UBARR[ci][1], r_, 0,0,0); \
        uint2 pk_; pk_.x = pack_bf16(r_[0], r_[1]); pk_.y = pack_bf16(r_[2], r_[3]); \
        *(uint2*)(slot_ + rt_*512 + lane*8) = pk_; \
      } \
    } \
  } \
} while (0)

// -------- consumer: Phase C for group QC from in-slot S + UB regs --------
#define CONSUME(QC, UBARR) do { \
  char* rbuf_ = lds + RBUF_OFF + ((QC) & 1) * 16384; \
  _Pragma("unroll") \
  for (int ci = 0; ci < 2; ++ci) { \
    const int lq_ = myw + 7 * ci; \
    if (lq_ < 8) { \
      const int qg_ = (QC) * 8 + lq_; \
      char* ss_ = rbuf_ + lq_ * 2048; \
      const short8 S0_ = *(const short8*)(ss_ + lane*16); \
      const short8 S1_ = *(const short8*)(ss_ + 1024 + lane*16); \
      _Pragma("unroll") \
      for (int rt_ = 0; rt_ < 4; ++rt_) { \
        const short8 k0_ = *(const short8*)(lds + FK_OFF + (((rt_*2 + 0)*64 + lane) << 4)); \
        const short8 k1_ = *(const short8*)(lds + FK_OFF + (((rt_*2 + 1)*64 + lane) << 4)); \
        const short8 w0_ = *(const short8*)(lds + FW_OFF + (((rt_*2 + 0)*64 + lane) << 4)); \
        const short8 w1_ = *(const short8*)(lds + FW_OFF + (((rt_*2 + 1)*64 + lane) << 4)); \
        floatx4 ty_ = {0.f, 0.f, 0.f, 0.f}; \
        ty_ = __builtin_amdgcn_mfma_f32_16x16x32_bf16(k0_, UBARR[ci][0], ty_, 0,0,0); \
        ty_ = __builtin_amdgcn_mfma_f32_16x16x32_bf16(k1_, UBARR[ci][1], ty_, 0,0,0); \
        ty_ = __builtin_amdgcn_mfma_f32_16x16x32_bf16(w0_, S0_,          ty_, 0,0,0); \
        ty_ = __builtin_amdgcn_mfma_f32_16x16x32_bf16(w1_, S1_,          ty_, 0,0,0); \
        if (act) { \
          const size_t rbase_ = (size_t)(qg_*64 + 16*rt_ + 4*quad); \
          _Pragma("unroll") \
          for (int r_ = 0; r_ < 4; ++r_) op[(rbase_ + r_) * DM] = ty_[r_]; \
        } \
      } \
    } \
  } \
} while (0)

// -------- scanner (wave 0): group QN: R -> entering-S in place --------
#define SCANQ(QN) do { \
  char* rbuf_ = lds + RBUF_OFF + ((QN) & 1) * 16384; \
  _Pragma("unroll 1") \
  for (int lq_ = 0; lq_ < 8; ++lq_) { \
    char* sp_ = rbuf_ + lq_ * 2048; \
    uint2 rb_[4]; \
    _Pragma("unroll") \
    for (int rt_ = 0; rt_ < 4; ++rt_) rb_[rt_] = *(const uint2*)(sp_ + rt_*512 + lane*8); \
    asm volatile("" ::: "memory"); \
    *(short8*)(sp_ + lane*16)        = B0; \
    *(short8*)(sp_ + 1024 + lane*16) = B1; \
    floatx4 acc_[4]; \
    _Pragma("unroll") \
    for (int rt_ = 0; rt_ < 4; ++rt_) { \
      floatx4 cs_; \
      cs_[0] = bflo(rb_[rt_].x); cs_[1] = bfhi(rb_[rt_].x); \
      cs_[2] = bflo(rb_[rt_].y); cs_[3] = bfhi(rb_[rt_].y); \
      floatx4 a0_ = __builtin_amdgcn_mfma_f32_16x16x32_bf16(At[rt_][0], B0, cs_, 0,0,0); \
      acc_[rt_]  = __builtin_amdgcn_mfma_f32_16x16x32_bf16(At[rt_][1], B1, a0_, 0,0,0); \
    } \
    unsigned pk_[4][2]; \
    _Pragma("unroll") \
    for (int rt_ = 0; rt_ < 4; ++rt_) { \
      pk_[rt_][0] = pack_bf16(acc_[rt_][0], acc_[rt_][1]); \
      pk_[rt_][1] = pack_bf16(acc_[rt_][2], acc_[rt_][3]); \
    } \
    union { short8 v; unsigned uu[4]; } nb0_, nb1_; \
    unsigned xa_, xb_; \
    xa_ = __shfl(pk_[0][0], srcA, 64); xb_ = __shfl(pk_[1][0], srcA, 64); nb0_.uu[0] = hi ? xb_ : xa_; \
    xa_ = __shfl(pk_[0][1], srcA, 64); xb_ = __shfl(pk_[1][1], srcA, 64); nb0_.uu[1] = hi ? xb_ : xa_; \
    xa_ = __shfl(pk_[0][0], srcB, 64); xb_ = __shfl(pk_[1][0], srcB, 64); nb0_.uu[2] = hi ? xb_ : xa_; \
    xa_ = __shfl(pk_[0][1], srcB, 64); xb_ = __shfl(pk_[1][1], srcB, 64); nb0_.uu[3] = hi ? xb_ : xa_; \
    xa_ = __shfl(pk_[2][0], srcA, 64); xb_ = __shfl(pk_[3][0], srcA, 64); nb1_.uu[0] = hi ? xb_ : xa_; \
    xa_ = __shfl(pk_[2][1], srcA, 64); xb_ = __shfl(pk_[3][1], srcA, 64); nb1_.uu[1] = hi ? xb_ : xa_; \
    xa_ = __shfl(pk_[2][0], srcB, 64); xb_ = __shfl(pk_[3][0], srcB, 64); nb1_.uu[2] = hi ? xb_ : xa_; \
    xa_ = __shfl(pk_[2][1], srcB, 64); xb_ = __shfl(pk_[3][1], srcB, 64); nb1_.uu[3] = hi ? xb_ : xa_; \
    B0 = nb0_.v; B1 = nb1_.v; \
  } \
} while (0)

__global__ __launch_bounds__(512, 4) void fused_kernel(
    const float* __restrict__ u, const float* __restrict__ ga,
    const float* __restrict__ gb, const float* __restrict__ gc,
    float* __restrict__ out)
{
  __shared__ __align__(16) char lds[LDS_TOTAL];
  unsigned short* G = (unsigned short*)lds;     // prep: rows 64..127, stride 128
  float* phi = (float*)(lds + PHI_OFF);
  float* kv  = (float*)(lds + KV_OFF);

  // block decode: i = m*128 + g2*2 + bp; head = 4*g2 + m  (the 4 heads
  // sharing a 64B u-line have ids differing by 128 -> same XCD slot)
  const int i = blockIdx.x;
  const int m = i >> 7, rr = i & 127;
  const int g2 = rr >> 1, bp = rr & 1;
  const int h = 4 * g2 + m;
  const int t = threadIdx.x;
  const int w = t >> 6, lane = t & 63;
  const int n16 = lane & 15, quad = lane >> 4;
  const int myw = w - 1;                        // producer index (w>=1)
  const bool act = (n16 < 8);                   // cols 0..7 active

  // ---------------- prep chains (no in-loop reductions) ----------------
  if (w < 2) {
    const float av = ga[h*KD + lane];
    const float an = av / wredsum(fabsf(av));   // mean(|rowsum|) >> eps
    if (w == 1) {
      phi[lane] = gc[h*KD + lane];              // phi[0..63] = c
      float g = an;                             // g_64 = A^64 e0 = a_n
      for (int p = 64; p < 128; ++p) {
        G[(64 + lane)*128 + (p - 64)] = f2bfru(g);   // T col m = g_{64+m}
        const float top = __shfl(g, 63, 64);
        const float gm1 = __shfl_up(g, 1, 64);
        g = (lane > 0 ? gm1 : 0.0f) + an * top;
      }
    } else {
      float v = gb[h*KD + lane];                // v_j = A^j b
      for (int j = 0; j < KD; ++j) {
        G[(64 + lane)*128 + 64 + (63 - j)] = f2bfru(v);  // V col m = v_{63-m}
        const float top = __shfl(v, 63, 64);
        const float vm1 = __shfl_up(v, 1, 64);
        v = (lane > 0 ? vm1 : 0.0f) + an * top;
      }
    }
  }
  __syncthreads();

  // ------- deferred dot products: phi[64..127] and kv[0..63] -------
  if (t < 128) {
    float acc = 0.f;
    for (int n = 0; n < 64; ++n)
      acc += phi[n] * bf2f(G[(64 + n)*128 + t]);
    if (t < 64) phi[64 + t] = acc;      // phi[p] = c . g_p
    else        kv[127 - t] = acc;      // kv[j] = c . v_j
  }
  __syncthreads();

  // ---------------- frag-major fills: V copy, W/K direct; wave0 At --------
  {
    const int f = t >> 6, l = t & 63;           // V: one 16B group per thread
    const int rt = f >> 1, kt = f & 1;
    const int ln = l & 15, lq2 = l >> 4;
    *(uint4*)(lds + FV_OFF + ((f*64 + l) << 4)) =
        *(const uint4*)(G + (64 + 16*rt + ln)*128 + 64 + 32*kt + 8*lq2);
  }
  {
    const int cgi = t >> 6, row = t & 63;       // W/K: 64 rows x 8 colgroups
    const int colg = cgi * 8;
    union { short8 v; unsigned short us[8]; } wb, kb;
#pragma unroll
    for (int jj = 0; jj < 8; ++jj) {
      wb.us[jj] = f2bfru(phi[row + 1 + colg + jj]);
      const int mm = colg + jj;
      kb.us[jj] = (mm <= row) ? f2bfru(kv[row - mm]) : (unsigned short)0;
    }
    *(short8*)(lds + FW_OFF + fmoff(row, colg)) = wb.v;
    *(short8*)(lds + FK_OFF + fmoff(row, colg)) = kb.v;
  }
  short8 At[4][2];
  if (w == 0) {
#pragma unroll
    for (int rt = 0; rt < 4; ++rt)
#pragma unroll
      for (int kt = 0; kt < 2; ++kt)
        At[rt][kt] = *(const short8*)(G + (64 + 16*rt + n16)*128 + 32*kt + quad*8);
  }
  __syncthreads();   // G (aliasing Rbuf) dead -> buffers usable

  // ---------------- main: 8 groups x 8 chunks, overlapped ----------------
  const size_t cs = (size_t)(2*bp + ((n16 >> 2) & 1)) * ((size_t)SL * DM)
                  + 4*h + (n16 & 3);
  const float* up = u + cs;
  float*       op = out + cs;
  const int srcA = n16 + 16*((2*quad) & 3);
  const int srcB = n16 + 16*((2*quad + 1) & 3);
  const bool hi = (quad >= 2);
  const short8 Z8 = {0,0,0,0,0,0,0,0};
  short8 B0 = Z8, B1 = Z8;                // scan carry (wave 0)
  short8 UBa[2][2], UBb[2][2];            // producer U frags, 2 groups live

  if (w != 0) PRODUCE(0, UBa);
  __syncthreads();

  if (w == 0) SCANQ(0); else PRODUCE(1, UBb);
  __syncthreads();
  if (w == 0) SCANQ(1); else { CONSUME(0, UBa); PRODUCE(2, UBa); }
  __syncthreads();
  if (w == 0) SCANQ(2); else { CONSUME(1, UBb); PRODUCE(3, UBb); }
  __syncthreads();
  if (w == 0) SCANQ(3); else { CONSUME(2, UBa); PRODUCE(4, UBa); }
  __syncthreads();
  if (w == 0) SCANQ(4); else { CONSUME(3, UBb); PRODUCE(5, UBb); }
  __syncthreads();
  if (w == 0) SCANQ(5); else { CONSUME(4, UBa); PRODUCE(6, UBa); }
  __syncthreads();
  if (w == 0) SCANQ(6); else { CONSUME(5, UBb); PRODUCE(7, UBb); }
  __syncthreads();
  if (w == 0) SCANQ(7); else CONSUME(6, UBa);
  __syncthreads();
  if (w != 0) CONSUME(7, UBb);
}

// ---------------------------------------------------------------- launch --
extern "C" void kernel_launch(void* const* d_in, const int* in_sizes, int n_in,
                              void* d_out, int out_size, void* d_ws, size_t ws_size,
                              hipStream_t stream)
{
  const float* u = (const float*)d_in[0];
  const float* a = (const float*)d_in[1];
  const float* b = (const float*)d_in[2];
  const float* c = (const float*)d_in[3];
  float* out = (float*)d_out;
  (void)d_ws; (void)ws_size; (void)in_sizes; (void)n_in; (void)out_size;

  fused_kernel<<<2 * NKH, 512, 0, stream>>>(u, a, b, c, out);
}

// Round 7
// 169.694 us; speedup vs baseline: 1.1261x; 1.1261x over previous
//
#include <hip/hip_runtime.h>

// CompanionSSM: 256 blocks (1 head each), 1024 threads = 16 waves, 4 waves/SIMD
// in ONE block (no co-residency gamble, no 64B-line splitting: all 16 cols =
// 4 batches x 4 ch active -> exact full-line write combining, r0/r5 proven).
// Three-stage pipeline, tri-buffered (slot = group % 3), 1 barrier per group:
//   wave 0   : serial scan of group g      (R slot g%3 -> entering-S in place)
//   waves 1-8: produce group g+1           (float4 + DPP qtr transpose ->
//              U-frags to LDS, R = V@U -> R slot (g+1)%3)
//   waves 8-15: consume group g-1          (Y = Toep@U + W@S from slot (g-1)%3,
//              qtr back -> float4 full-line stores)
// All three touch disjoint slots every iteration (mod-3) -> race-free.
// IO: 4 vector load + 4 vector store instr per chunk (vs 16+16 scalar).
// Prep: r5's no-reduction chains + deferred dots; V/W/K frag-major (r3/r6).
// LDS: R 3x16KB + U 3x16KB + frags 24KB + phi/kv = 121KB (1 block/CU).

#define NKH 256
#define KD  64
#define SL  4096
#define DM  1024

typedef __attribute__((ext_vector_type(8))) short short8;
typedef __attribute__((ext_vector_type(4))) float floatx4;

#define RBUF_OFF  0
#define UBUF_OFF  49152
#define FV_OFF    98304
#define FW_OFF    106496
#define FK_OFF    114688
#define PHI_OFF   122880
#define KV_OFF    123392
#define LDS_TOTAL 123648

static __device__ __forceinline__ unsigned pack_bf16(float a, float b) {
  union { float f; unsigned u; } ua, ub;
  ua.f = a; ub.f = b;
  return __builtin_amdgcn_perm(ub.u + 0x8000u, ua.u + 0x8000u, 0x07060302u);
}
static __device__ __forceinline__ unsigned short f2bfru(float x) {
  union { float f; unsigned u; } v; v.f = x;
  return (unsigned short)((v.u + 0x8000u) >> 16);
}
static __device__ __forceinline__ float bflo(unsigned d) {
  union { unsigned u; float f; } v; v.u = d << 16; return v.f;
}
static __device__ __forceinline__ float bfhi(unsigned d) {
  union { unsigned u; float f; } v; v.u = d & 0xffff0000u; return v.f;
}
static __device__ __forceinline__ float bf2f(unsigned short s) {
  union { unsigned u; float f; } v; v.u = ((unsigned)s) << 16; return v.f;
}
static __device__ __forceinline__ float wredsum(float x) {
#pragma unroll
  for (int off = 32; off; off >>= 1) x += __shfl_xor(x, off, 64);
  return x;
}
// 4x4 transpose across a DPP quad (lanes 4k..4k+3, c = lane&3).
// Input: lane c holds v[0..3] = M[c][*].  Output: lane c holds r[k] = M[k][c].
static __device__ __forceinline__ float4 qtr(float4 v, int c) {
  const bool c1 = (c & 1) != 0, c2 = (c & 2) != 0;
  float a01 = __shfl_xor(v.y, 1, 64), a10 = __shfl_xor(v.x, 1, 64);
  float a23 = __shfl_xor(v.w, 1, 64), a32 = __shfl_xor(v.z, 1, 64);
  float t0 = c1 ? a01 : v.x, t1 = c1 ? v.y : a10;
  float t2 = c1 ? a23 : v.z, t3 = c1 ? v.w : a32;
  float b02 = __shfl_xor(t2, 2, 64), b20 = __shfl_xor(t0, 2, 64);
  float b13 = __shfl_xor(t3, 2, 64), b31 = __shfl_xor(t1, 2, 64);
  float4 r;
  r.x = c2 ? b02 : t0; r.y = c2 ? b13 : t1;
  r.z = c2 ? t2 : b20; r.w = c2 ? t3 : b31;
  return r;
}
// frag-major 16B-group byte offset for 64x64 bf16: element (row, colg..colg+7)
static __device__ __forceinline__ int fmoff(int row, int colg) {
  return ((((row >> 4) * 2 + (colg >> 5)) * 64 + ((colg >> 3) & 3) * 16 + (row & 15)) << 4);
}

// -------- producer wave (1..8): chunk pw of group QN -> slot SL3 --------
// lane = quad*16 + b*4 + rr: loads float4 (4 ch of head h) at 16 rows x 4
// batches per instruction; qtr within quads -> B-frag cols n16 = 4b+rr.
#define PRODUCE(QN, SL3) do { \
  const int qg_ = (QN) * 8 + pw; \
  const float4 L00_ = *(const float4*)(upb + (size_t)(qg_*64 +      q8 +     rr) * DM); \
  const float4 L01_ = *(const float4*)(upb + (size_t)(qg_*64 +      q8 + 4 + rr) * DM); \
  const float4 L10_ = *(const float4*)(upb + (size_t)(qg_*64 + 32 + q8 +     rr) * DM); \
  const float4 L11_ = *(const float4*)(upb + (size_t)(qg_*64 + 32 + q8 + 4 + rr) * DM); \
  const float4 W00_ = qtr(L00_, rr), W01_ = qtr(L01_, rr); \
  const float4 W10_ = qtr(L10_, rr), W11_ = qtr(L11_, rr); \
  union { short8 v; unsigned s4[4]; } u0_, u1_; \
  u0_.s4[0] = pack_bf16(W00_.x, W00_.y); u0_.s4[1] = pack_bf16(W00_.z, W00_.w); \
  u0_.s4[2] = pack_bf16(W01_.x, W01_.y); u0_.s4[3] = pack_bf16(W01_.z, W01_.w); \
  u1_.s4[0] = pack_bf16(W10_.x, W10_.y); u1_.s4[1] = pack_bf16(W10_.z, W10_.w); \
  u1_.s4[2] = pack_bf16(W11_.x, W11_.y); u1_.s4[3] = pack_bf16(W11_.z, W11_.w); \
  char* us_ = lds + UBUF_OFF + (SL3) * 16384 + pw * 2048; \
  *(short8*)(us_ + lane*16)        = u0_.v; \
  *(short8*)(us_ + 1024 + lane*16) = u1_.v; \
  char* slot_ = lds + RBUF_OFF + (SL3) * 16384 + pw * 2048; \
  _Pragma("unroll") \
  for (int rt_ = 0; rt_ < 4; ++rt_) { \
    const short8 v0_ = *(const short8*)(lds + FV_OFF + (((rt_*2 + 0)*64 + lane) << 4)); \
    const short8 v1_ = *(const short8*)(lds + FV_OFF + (((rt_*2 + 1)*64 + lane) << 4)); \
    floatx4 r_ = {0.f, 0.f, 0.f, 0.f}; \
    r_ = __builtin_amdgcn_mfma_f32_16x16x32_bf16(v0_, u0_.v, r_, 0,0,0); \
    r_ = __builtin_amdgcn_mfma_f32_16x16x32_bf16(v1_, u1_.v, r_, 0,0,0); \
    uint2 pk_; pk_.x = pack_bf16(r_[0], r_[1]); pk_.y = pack_bf16(r_[2], r_[3]); \
    *(uint2*)(slot_ + rt_*512 + lane*8) = pk_; \
  } \
} while (0)

// -------- consumer wave (8..15): chunk cw of group QC from slot SL3 --------
#define CONSUME(QC, SL3) do { \
  const int qg_ = (QC) * 8 + cw; \
  char* ss_ = lds + RBUF_OFF + (SL3) * 16384 + cw * 2048; \
  const short8 S0_ = *(const short8*)(ss_ + lane*16); \
  const short8 S1_ = *(const short8*)(ss_ + 1024 + lane*16); \
  char* us_ = lds + UBUF_OFF + (SL3) * 16384 + cw * 2048; \
  const short8 U0_ = *(const short8*)(us_ + lane*16); \
  const short8 U1_ = *(const short8*)(us_ + 1024 + lane*16); \
  _Pragma("unroll") \
  for (int rt_ = 0; rt_ < 4; ++rt_) { \
    const short8 k0_ = *(const short8*)(lds + FK_OFF + (((rt_*2 + 0)*64 + lane) << 4)); \
    const short8 k1_ = *(const short8*)(lds + FK_OFF + (((rt_*2 + 1)*64 + lane) << 4)); \
    const short8 w0_ = *(const short8*)(lds + FW_OFF + (((rt_*2 + 0)*64 + lane) << 4)); \
    const short8 w1_ = *(const short8*)(lds + FW_OFF + (((rt_*2 + 1)*64 + lane) << 4)); \
    floatx4 ty_ = {0.f, 0.f, 0.f, 0.f}; \
    ty_ = __builtin_amdgcn_mfma_f32_16x16x32_bf16(k0_, U0_, ty_, 0,0,0); \
    ty_ = __builtin_amdgcn_mfma_f32_16x16x32_bf16(k1_, U1_, ty_, 0,0,0); \
    ty_ = __builtin_amdgcn_mfma_f32_16x16x32_bf16(w0_, S0_, ty_, 0,0,0); \
    ty_ = __builtin_amdgcn_mfma_f32_16x16x32_bf16(w1_, S1_, ty_, 0,0,0); \
    float4 yv_; yv_.x = ty_[0]; yv_.y = ty_[1]; yv_.z = ty_[2]; yv_.w = ty_[3]; \
    const float4 tw_ = qtr(yv_, rr); \
    *(float4*)(opb + (size_t)(qg_*64 + 16*rt_ + 4*quad + rr) * DM) = tw_; \
  } \
} while (0)

// -------- scanner (wave 0): group QN in slot SL3: R -> entering-S in place --
#define SCANQ(QN, SL3) do { \
  char* rbuf_ = lds + RBUF_OFF + (SL3) * 16384; \
  _Pragma("unroll 1") \
  for (int lq_ = 0; lq_ < 8; ++lq_) { \
    char* sp_ = rbuf_ + lq_ * 2048; \
    uint2 rb_[4]; \
    _Pragma("unroll") \
    for (int rt_ = 0; rt_ < 4; ++rt_) rb_[rt_] = *(const uint2*)(sp_ + rt_*512 + lane*8); \
    asm volatile("" ::: "memory"); \
    *(short8*)(sp_ + lane*16)        = B0; \
    *(short8*)(sp_ + 1024 + lane*16) = B1; \
    floatx4 acc_[4]; \
    _Pragma("unroll") \
    for (int rt_ = 0; rt_ < 4; ++rt_) { \
      floatx4 cs_; \
      cs_[0] = bflo(rb_[rt_].x); cs_[1] = bfhi(rb_[rt_].x); \
      cs_[2] = bflo(rb_[rt_].y); cs_[3] = bfhi(rb_[rt_].y); \
      floatx4 a0_ = __builtin_amdgcn_mfma_f32_16x16x32_bf16(At[rt_][0], B0, cs_, 0,0,0); \
      acc_[rt_]  = __builtin_amdgcn_mfma_f32_16x16x32_bf16(At[rt_][1], B1, a0_, 0,0,0); \
    } \
    unsigned pk_[4][2]; \
    _Pragma("unroll") \
    for (int rt_ = 0; rt_ < 4; ++rt_) { \
      pk_[rt_][0] = pack_bf16(acc_[rt_][0], acc_[rt_][1]); \
      pk_[rt_][1] = pack_bf16(acc_[rt_][2], acc_[rt_][3]); \
    } \
    union { short8 v; unsigned uu[4]; } nb0_, nb1_; \
    unsigned xa_, xb_; \
    xa_ = __shfl(pk_[0][0], srcA, 64); xb_ = __shfl(pk_[1][0], srcA, 64); nb0_.uu[0] = hi ? xb_ : xa_; \
    xa_ = __shfl(pk_[0][1], srcA, 64); xb_ = __shfl(pk_[1][1], srcA, 64); nb0_.uu[1] = hi ? xb_ : xa_; \
    xa_ = __shfl(pk_[0][0], srcB, 64); xb_ = __shfl(pk_[1][0], srcB, 64); nb0_.uu[2] = hi ? xb_ : xa_; \
    xa_ = __shfl(pk_[0][1], srcB, 64); xb_ = __shfl(pk_[1][1], srcB, 64); nb0_.uu[3] = hi ? xb_ : xa_; \
    xa_ = __shfl(pk_[2][0], srcA, 64); xb_ = __shfl(pk_[3][0], srcA, 64); nb1_.uu[0] = hi ? xb_ : xa_; \
    xa_ = __shfl(pk_[2][1], srcA, 64); xb_ = __shfl(pk_[3][1], srcA, 64); nb1_.uu[1] = hi ? xb_ : xa_; \
    xa_ = __shfl(pk_[2][0], srcB, 64); xb_ = __shfl(pk_[3][0], srcB, 64); nb1_.uu[2] = hi ? xb_ : xa_; \
    xa_ = __shfl(pk_[2][1], srcB, 64); xb_ = __shfl(pk_[3][1], srcB, 64); nb1_.uu[3] = hi ? xb_ : xa_; \
    B0 = nb0_.v; B1 = nb1_.v; \
  } \
} while (0)

__global__ __launch_bounds__(1024, 4) void fused_kernel(
    const float* __restrict__ u, const float* __restrict__ ga,
    const float* __restrict__ gb, const float* __restrict__ gc,
    float* __restrict__ out)
{
  __shared__ __align__(16) char lds[LDS_TOTAL];
  unsigned short* G = (unsigned short*)lds;     // prep: rows 64..127, stride 128
  float* phi = (float*)(lds + PHI_OFF);
  float* kv  = (float*)(lds + KV_OFF);

  const int i = blockIdx.x;
  const int h = 8 * (i & 31) + (i >> 5);        // co-line heads -> same XCD
  const int t = threadIdx.x;
  const int w = t >> 6, lane = t & 63;
  const int n16 = lane & 15, quad = lane >> 4;
  const int rr = lane & 3, q8 = quad * 8, bqi = (lane >> 2) & 3;
  const int pw = w - 1;                         // producer chunk (waves 1..8)
  const int cw = w - 8;                         // consumer chunk (waves 8..15)

  // ---------------- prep chains (waves 0,1; no in-loop reductions) --------
  if (w < 2) {
    const float av = ga[h*KD + lane];
    const float an = av / wredsum(fabsf(av));   // mean(|rowsum|) >> eps
    if (w == 1) {
      phi[lane] = gc[h*KD + lane];              // phi[0..63] = c
      float g = an;                             // g_64 = A^64 e0 = a_n
      for (int p = 64; p < 128; ++p) {
        G[(64 + lane)*128 + (p - 64)] = f2bfru(g);   // T col m = g_{64+m}
        const float top = __shfl(g, 63, 64);
        const float gm1 = __shfl_up(g, 1, 64);
        g = (lane > 0 ? gm1 : 0.0f) + an * top;
      }
    } else {
      float v = gb[h*KD + lane];                // v_j = A^j b
      for (int j = 0; j < KD; ++j) {
        G[(64 + lane)*128 + 64 + (63 - j)] = f2bfru(v);  // V col m = v_{63-m}
        const float top = __shfl(v, 63, 64);
        const float vm1 = __shfl_up(v, 1, 64);
        v = (lane > 0 ? vm1 : 0.0f) + an * top;
      }
    }
  }
  __syncthreads();

  // ------- deferred dot products: phi[64..127] and kv[0..63] -------
  if (t < 128) {
    float acc = 0.f;
    for (int n = 0; n < 64; ++n)
      acc += phi[n] * bf2f(G[(64 + n)*128 + t]);
    if (t < 64) phi[64 + t] = acc;      // phi[p] = c . g_p
    else        kv[127 - t] = acc;      // kv[j] = c . v_j
  }
  __syncthreads();

  // ---------------- frag-major fills: V copy, W/K direct; wave0 At --------
  if (t < 512) {
    const int f = t >> 6, l = t & 63;           // V: one 16B group per thread
    const int rt = f >> 1, kt = f & 1;
    const int ln = l & 15, lq2 = l >> 4;
    *(uint4*)(lds + FV_OFF + ((f*64 + l) << 4)) =
        *(const uint4*)(G + (64 + 16*rt + ln)*128 + 64 + 32*kt + 8*lq2);
  }
  if (t < 512) {
    const int cgi = t >> 6, row = t & 63;       // W/K: 64 rows x 8 colgroups
    const int colg = cgi * 8;
    union { short8 v; unsigned short us[8]; } wb, kb;
#pragma unroll
    for (int jj = 0; jj < 8; ++jj) {
      wb.us[jj] = f2bfru(phi[row + 1 + colg + jj]);
      const int mm = colg + jj;
      kb.us[jj] = (mm <= row) ? f2bfru(kv[row - mm]) : (unsigned short)0;
    }
    *(short8*)(lds + FW_OFF + fmoff(row, colg)) = wb.v;
    *(short8*)(lds + FK_OFF + fmoff(row, colg)) = kb.v;
  }
  short8 At[4][2];
  if (w == 0) {
#pragma unroll
    for (int rt = 0; rt < 4; ++rt)
#pragma unroll
      for (int kt = 0; kt < 2; ++kt)
        At[rt][kt] = *(const short8*)(G + (64 + 16*rt + n16)*128 + 32*kt + quad*8);
  }
  __syncthreads();   // G (aliasing Rbuf slots 0/1) dead -> buffers usable

  // ---------------- main: 8 groups x 8 chunks, 3-stage pipeline ----------
  const float* upb = u   + (size_t)bqi * ((size_t)SL * DM) + 4*h;
  float*       opb = out + (size_t)bqi * ((size_t)SL * DM) + 4*h;
  const int srcA = n16 + 16*((2*quad) & 3);
  const int srcB = n16 + 16*((2*quad + 1) & 3);
  const bool hi = (quad >= 2);
  const short8 Z8 = {0,0,0,0,0,0,0,0};
  short8 B0 = Z8, B1 = Z8;                // scan carry (wave 0)

  if (w >= 1 && w <= 8) PRODUCE(0, 0);
  __syncthreads();

  // iter 0: scan(0,s0) || produce(1,s1)
  if (w == 0) SCANQ(0, 0);
  if (w >= 1 && w <= 8) PRODUCE(1, 1);
  __syncthreads();
  // iter 1..6: scan(g) || produce(g+1) || consume(g-1)   (slots mod 3)
  if (w == 0) SCANQ(1, 1);
  if (w >= 1 && w <= 8) PRODUCE(2, 2);
  if (w >= 8) CONSUME(0, 0);
  __syncthreads();
  if (w == 0) SCANQ(2, 2);
  if (w >= 1 && w <= 8) PRODUCE(3, 0);
  if (w >= 8) CONSUME(1, 1);
  __syncthreads();
  if (w == 0) SCANQ(3, 0);
  if (w >= 1 && w <= 8) PRODUCE(4, 1);
  if (w >= 8) CONSUME(2, 2);
  __syncthreads();
  if (w == 0) SCANQ(4, 1);
  if (w >= 1 && w <= 8) PRODUCE(5, 2);
  if (w >= 8) CONSUME(3, 0);
  __syncthreads();
  if (w == 0) SCANQ(5, 2);
  if (w >= 1 && w <= 8) PRODUCE(6, 0);
  if (w >= 8) CONSUME(4, 1);
  __syncthreads();
  if (w == 0) SCANQ(6, 0);
  if (w >= 1 && w <= 8) PRODUCE(7, 1);
  if (w >= 8) CONSUME(5, 2);
  __syncthreads();
  // iter 7: scan(7,s1) || consume(6,s0)
  if (w == 0) SCANQ(7, 1);
  if (w >= 8) CONSUME(6, 0);
  __syncthreads();
  // tail: consume(7,s1)
  if (w >= 8) CONSUME(7, 1);
}

// ---------------------------------------------------------------- launch --
extern "C" void kernel_launch(void* const* d_in, const int* in_sizes, int n_in,
                              void* d_out, int out_size, void* d_ws, size_t ws_size,
                              hipStream_t stream)
{
  const float* u = (const float*)d_in[0];
  const float* a = (const float*)d_in[1];
  const float* b = (const float*)d_in[2];
  const float* c = (const float*)d_in[3];
  float* out = (float*)d_out;
  (void)d_ws; (void)ws_size; (void)in_sizes; (void)n_in; (void)out_size;

  fused_kernel<<<NKH, 1024, 0, stream>>>(u, a, b, c, out);
}